// Round 9
// baseline (388.598 us; speedup 1.0000x reference)
//
#include <hip/hip_runtime.h>
#include <hip/hip_fp16.h>
#include <math.h>

#define N_ENT 50000
#define N_USR 10000
#define NN    60000
#define DD    64
#define H0    128
#define ENCD  32
#define RR    16
#define NB    256
#define BSH   8
#define NBU   235   // ceil(NN/256): buckets actually used

__device__ __forceinline__ float4 ld4(const float* p){ return *reinterpret_cast<const float4*>(p); }
__device__ __forceinline__ void st4(float* p, float4 v){ *reinterpret_cast<float4*>(p) = v; }

// Fused: [0,nbAE) = autoencoder (64 nodes/block); [nbAE,nbAE+nbTh) = edge histogram;
// [nbAE+nbTh, +4) = w_sum reduction. 512 threads everywhere.
// AE: x read from global (L2-hot) into registers; h1/h2 + enc staged in 41.7KB LDS
// [feat][node] stride-65 (conflict-free) -> 3 blocks/CU, 6 waves/SIMD.
__global__ __launch_bounds__(512, 6) void k_ae_hist(const float* __restrict__ ent, const float* __restrict__ usr,
    const float* __restrict__ eW0, const float* __restrict__ eb0,
    const float* __restrict__ eW1, const float* __restrict__ eb1,
    const float* __restrict__ dW0c, const float* __restrict__ db0,
    const float* __restrict__ dW1c, const float* __restrict__ db1,
    float* __restrict__ enc, float* __restrict__ loss_out,
    const int* __restrict__ edst, int* __restrict__ bktCnt,
    const float* __restrict__ Wr1, const float* __restrict__ Wr2, float* __restrict__ wsum,
    int E_, int nbAE, int nbTh){
  __shared__ float hs[H0][65];     // 33.3 KB (h1, then h2)
  __shared__ float es[ENCD][65];   // 8.3 KB
  __shared__ float sred[8];
  int bid = blockIdx.x;
  int t = threadIdx.x;

  if (bid >= nbAE){
    int rb = bid - nbAE;
    if (rb < nbTh){
      // ---- histogram branch: 8192 edges/block ----
      int* hh = (int*)&hs[0][0];
      if (t < NB) hh[t] = 0;
      __syncthreads();
      int i0 = rb*8192;
      #pragma unroll
      for (int k=0;k<16;k++){
        int e = i0 + k*512 + t;
        if (e < E_) atomicAdd(&hh[((unsigned)edst[e])>>BSH], 1);
      }
      __syncthreads();
      if (t < NB){ int c = hh[t]; if (c) atomicAdd(&bktCnt[t], c); }
    } else {
      // ---- wsum branch: wsum[layer][r*64+j] = sum_k Wr[r][j][k] ----
      int i = (rb - nbTh)*512 + t;
      if (i < 2*RR*DD){
        const float* Wr = (i < RR*DD) ? Wr1 : Wr2;
        int loc = i & (RR*DD - 1);
        const float* p = Wr + (size_t)loc*32;
        float s = 0.f;
        #pragma unroll
        for (int k=0;k<32;k++) s += p[k];
        wsum[i] = s;
      }
    }
    return;
  }

  // ---- AE branch ----
  int nl = t & 63;
  int wid = __builtin_amdgcn_readfirstlane(t >> 6);   // 0..7
  int gnode = bid*64 + nl;
  bool valid = gnode < NN;
  const float* xr = valid ? ((gnode < N_ENT) ? ent + (size_t)gnode*DD
                                             : usr + (size_t)(gnode-N_ENT)*DD)
                          : ent;   // safe dummy row for tail lanes

  // phase1: h1[j0..j0+15] = relu(x @ eW0 + eb0); x streamed from global in 16-float chunks
  {
    int j0 = wid*16;
    float acc[16];
    #pragma unroll
    for (int k=0;k<16;k++) acc[k]=eb0[j0+k];
    #pragma unroll
    for (int dc=0; dc<DD; dc+=16){
      float xv[16];
      #pragma unroll
      for (int q=0;q<4;q++){
        float4 v = ld4(xr + dc + 4*q);
        xv[4*q]=v.x; xv[4*q+1]=v.y; xv[4*q+2]=v.z; xv[4*q+3]=v.w;
      }
      #pragma unroll
      for (int dd=0; dd<16; dd++){
        const float* w = eW0 + (size_t)(dc+dd)*H0 + j0;
        #pragma unroll
        for (int k=0;k<16;k++) acc[k]=fmaf(xv[dd], w[k], acc[k]);
      }
    }
    #pragma unroll
    for (int k=0;k<16;k++) hs[j0+k][nl]=fmaxf(acc[k],0.f);
  }
  __syncthreads();

  // phase2: enc[k0..k0+3] = h1 @ eW1 + eb1
  {
    int k0 = wid*4;
    float acc[4];
    #pragma unroll
    for (int k=0;k<4;k++) acc[k]=eb1[k0+k];
    #pragma unroll 4
    for (int j=0;j<H0;j++){
      float hv = hs[j][nl];
      const float* w = eW1 + (size_t)j*ENCD + k0;
      #pragma unroll
      for (int k=0;k<4;k++) acc[k]=fmaf(hv,w[k],acc[k]);
    }
    #pragma unroll
    for (int k=0;k<4;k++) es[k0+k][nl]=acc[k];
  }
  __syncthreads();

  // coalesced enc writeout: thread t stores 16B of node (t>>3)
  {
    int n2 = t >> 3;
    int k2 = (t & 7) * 4;
    int gn2 = bid*64 + n2;
    if (gn2 < NN){
      float4 a;
      a.x=es[k2+0][n2]; a.y=es[k2+1][n2]; a.z=es[k2+2][n2]; a.w=es[k2+3][n2];
      st4(enc + (size_t)gn2*ENCD + k2, a);
    }
  }

  // phase3: h2[j0..j0+15] = relu(enc @ dW0 + db0)
  {
    int j0 = wid*16;
    float acc[16];
    #pragma unroll
    for (int k=0;k<16;k++) acc[k]=db0[j0+k];
    #pragma unroll 4
    for (int d=0;d<ENCD;d++){
      float x = es[d][nl];
      const float* w = dW0c + (size_t)d*H0 + j0;
      #pragma unroll
      for (int k=0;k<16;k++) acc[k]=fmaf(x,w[k],acc[k]);
    }
    #pragma unroll
    for (int k=0;k<16;k++) hs[j0+k][nl]=fmaxf(acc[k],0.f);
  }
  __syncthreads();

  // phase4: dec[c0..c0+7] = h2 @ dW1 + db1 ; loss vs x re-read from global
  float part = 0.f;
  {
    int c0 = wid*8;
    float acc[8];
    #pragma unroll
    for (int k=0;k<8;k++) acc[k]=db1[c0+k];
    #pragma unroll 4
    for (int j=0;j<H0;j++){
      float hv = hs[j][nl];
      const float* w = dW1c + (size_t)j*DD + c0;
      #pragma unroll
      for (int k=0;k<8;k++) acc[k]=fmaf(hv,w[k],acc[k]);
    }
    if (valid){
      float xl[8];
      float4 v0 = ld4(xr + c0), v1 = ld4(xr + c0 + 4);
      xl[0]=v0.x; xl[1]=v0.y; xl[2]=v0.z; xl[3]=v0.w;
      xl[4]=v1.x; xl[5]=v1.y; xl[6]=v1.z; xl[7]=v1.w;
      #pragma unroll
      for (int k=0;k<8;k++){ float d_ = acc[k]-xl[k]; part = fmaf(d_,d_,part); }
    }
  }
  #pragma unroll
  for (int off=32; off>0; off>>=1) part += __shfl_down(part, off, 64);
  if ((t&63)==0) sred[wid] = part;
  __syncthreads();
  if (t==0){
    float s = 0.f;
    #pragma unroll
    for (int k=0;k<8;k++) s += sred[k];
    atomicAdd(loss_out, s * (1.0f/((float)NN*(float)DD)));
  }
}

// exclusive scan of 256 bucket counts (one block)
__global__ __launch_bounds__(256) void k_scan256(const int* __restrict__ bktCnt, int* __restrict__ bktBase){
  __shared__ int wps[4];
  int t = threadIdx.x;
  int v = bktCnt[t];
  int x = v;
  #pragma unroll
  for (int off=1; off<64; off<<=1){
    int y = __shfl_up(x, off, 64);
    if ((t & 63) >= off) x += y;
  }
  if ((t & 63) == 63) wps[t >> 6] = x;
  __syncthreads();
  if (t < 4){
    int wv = wps[t];
    int wx = wv;
    #pragma unroll
    for (int off=1; off<4; off<<=1){
      int y = __shfl_up(wx, off, 4);
      if (t >= off) wx += y;
    }
    wps[t] = wx - wv;
  }
  __syncthreads();
  bktBase[t] = (x - v) + wps[t >> 6];
}

// bucketed append: each block reserves exclusive contiguous chunks per bucket
__global__ __launch_bounds__(256) void k_bucketA(const int* __restrict__ esrc, const int* __restrict__ edst,
    const int* __restrict__ erel, const int* __restrict__ bktBase, int* __restrict__ bktFill,
    unsigned* __restrict__ bktData, int E_){
  __shared__ int h[NB];
  __shared__ int gbase[NB];
  h[threadIdx.x]=0;
  __syncthreads();
  int i0 = blockIdx.x*4096;
  int dcache[16];
  #pragma unroll
  for (int k=0;k<16;k++){
    int e = i0 + k*256 + threadIdx.x;
    int d = (e < E_) ? edst[e] : -1;
    dcache[k] = d;
    if (d >= 0) atomicAdd(&h[((unsigned)d)>>BSH], 1);
  }
  __syncthreads();
  {
    int c = h[threadIdx.x];
    int off = c ? atomicAdd(&bktFill[threadIdx.x], c) : 0;
    gbase[threadIdx.x] = bktBase[threadIdx.x] + off;
    h[threadIdx.x] = 0;   // reuse as local fill
  }
  __syncthreads();
  #pragma unroll
  for (int k=0;k<16;k++){
    int e = i0 + k*256 + threadIdx.x;
    if (e >= E_) continue;
    int d = dcache[k];
    int b = ((unsigned)d) >> BSH;
    int slot = atomicAdd(&h[b], 1);
    unsigned rec = (unsigned)esrc[e] | ((unsigned)erel[e] << 16) | ((unsigned)(d & 0xFF) << 20);
    bktData[(size_t)gbase[b] + slot] = rec;
  }
}

// per-bucket CSR build: counts+scan in LDS, localized writes; keeps dl bits in packed
__global__ __launch_bounds__(256) void k_buildB(const unsigned* __restrict__ bktData,
    const int* __restrict__ bktBase, const int* __restrict__ bktCnt,
    int* __restrict__ rowp, int* __restrict__ packed){
  __shared__ int cnt[NB];
  __shared__ int start[NB];
  __shared__ int wps[4];
  int b = blockIdx.x;
  int base = bktBase[b];
  int n = bktCnt[b];
  int t = threadIdx.x;
  cnt[t] = 0;
  __syncthreads();
  for (int i=t; i<n; i+=256) atomicAdd(&cnt[(bktData[base+i] >> 20) & 0xFF], 1);
  __syncthreads();
  int v = cnt[t];
  cnt[t] = 0;                       // reset for fill pass
  int x = v;
  #pragma unroll
  for (int off=1; off<64; off<<=1){
    int y = __shfl_up(x, off, 64);
    if ((t & 63) >= off) x += y;
  }
  if ((t & 63) == 63) wps[t >> 6] = x;
  __syncthreads();
  if (t < 4){
    int wv = wps[t];
    int wx = wv;
    #pragma unroll
    for (int off=1; off<4; off<<=1){
      int y = __shfl_up(wx, off, 4);
      if (t >= off) wx += y;
    }
    wps[t] = wx - wv;
  }
  __syncthreads();
  int sv = (x - v) + wps[t >> 6];   // exclusive prefix over dl
  start[t] = sv;
  int node = (b << BSH) + t;
  if (node <= NN) rowp[node] = base + sv;
  __syncthreads();
  for (int i=t; i<n; i+=256){
    unsigned r = bktData[base+i];
    int dl = (r >> 20) & 0xFF;
    int p = start[dl] + atomicAdd(&cnt[dl], 1);
    packed[base + p] = (int)r;      // keep src|rel|dl
  }
}

// Per-node per-relation gate partials + f16 tables:
// dA[n][r] (f32, dst side), dbrec[n][r] (f16, src side), xrec[n][0:32] (f16 features)
__global__ __launch_bounds__(256) void k_dots(const float* __restrict__ x, const float* __restrict__ wsum,
    float* __restrict__ dA, __half* __restrict__ dbrec, __half* __restrict__ xrec){
  __shared__ float wl[RR*DD];                  // wl[j*16+rel] = wsum[rel*64+j]
  for (int i = threadIdx.x; i < RR*DD; i += 256){
    int r = i & 15; int j = i >> 4;
    wl[i] = wsum[r*DD + j];
  }
  __syncthreads();
  int t = blockIdx.x*256 + threadIdx.x;
  if (t >= NN*RR) return;
  int n = t >> 4, r = t & 15;
  const float* xr = x + (size_t)n*ENCD;
  float a = 0.f, b = 0.f;
  float xlo = 0.f, xhi = 0.f;
  #pragma unroll
  for (int q=0;q<8;q++){
    float4 v = ld4(xr + 4*q);
    int j = 4*q;
    if (r >= j && r < j+4){ float tmp[4]={v.x,v.y,v.z,v.w}; xlo = tmp[r-j]; }
    if (r+16 >= j && r+16 < j+4){ float tmp[4]={v.x,v.y,v.z,v.w}; xhi = tmp[r+16-j]; }
    a = fmaf(v.x, wl[(j+0)*16 + r], a);
    a = fmaf(v.y, wl[(j+1)*16 + r], a);
    a = fmaf(v.z, wl[(j+2)*16 + r], a);
    a = fmaf(v.w, wl[(j+3)*16 + r], a);
    b = fmaf(v.x, wl[(32+j+0)*16 + r], b);
    b = fmaf(v.y, wl[(32+j+1)*16 + r], b);
    b = fmaf(v.z, wl[(32+j+2)*16 + r], b);
    b = fmaf(v.w, wl[(32+j+3)*16 + r], b);
  }
  dA[t] = a;
  dbrec[t] = __float2half(b);
  xrec[(size_t)n*32 + r]      = __float2half(xlo);
  xrec[(size_t)n*32 + 16 + r] = __float2half(xhi);
}

// Per-edge gate pass: sequential packed stream, L2-resident dbrec gather, f16 gate stream out
__global__ __launch_bounds__(256) void k_gates(const int* __restrict__ packed,
    const int* __restrict__ bktBase, const int* __restrict__ bktCnt,
    const float* __restrict__ dA, const __half* __restrict__ dbrec, __half* __restrict__ gat){
  int b = blockIdx.x >> 2, g = blockIdx.x & 3;
  int base = bktBase[b], n = bktCnt[b];
  int lo = (n*g) >> 2, hi = (n*(g+1)) >> 2;
  for (int i = lo + (int)threadIdx.x; i < hi; i += 256){
    int p = packed[base+i];
    int s = p & 0xFFFF;
    int r = (p >> 16) & 15;
    int dl = (p >> 20) & 0xFF;
    int dst = (b << BSH) | dl;
    float z = dA[dst*16 + r] + __half2float(dbrec[s*16 + r]);
    gat[base+i] = __float2half(1.f/(1.f + __expf(-z)));
  }
}

// Scatter-mean via CSR gather: 32 lanes/node, even/odd edge halves, shfl_xor combine
__global__ __launch_bounds__(256) void k_agg(const __half2* __restrict__ xrec2, const int* __restrict__ packed,
    const __half* __restrict__ gat, const int* __restrict__ rowp, float* __restrict__ agg){
  int node = blockIdx.x*8 + (threadIdx.x >> 5);
  int l = threadIdx.x & 31;
  int half = l >> 4;
  int l16 = l & 15;
  if (node >= NN) return;
  int beg = rowp[node], end = rowp[node+1];
  float ax = 0.f, ay = 0.f;
  #pragma unroll 2
  for (int i = beg + half; i < end; i += 2){
    int p = packed[i];
    int s = p & 0xFFFF;
    float g = __half2float(gat[i]);
    float2 fx = __half22float2(xrec2[(size_t)s*16 + l16]);
    ax = fmaf(fx.x, g, ax);
    ay = fmaf(fx.y, g, ay);
  }
  ax += __shfl_xor(ax, 16, 32);
  ay += __shfl_xor(ay, 16, 32);
  if (half == 0){
    int deg = end - beg;
    float inv = (deg > 0) ? 1.f/(float)deg : 0.f;
    float2 o; o.x = ax*inv; o.y = ay*inv;
    *reinterpret_cast<float2*>(&agg[(size_t)node*ENCD + 2*l16]) = o;
  }
}

// out = leaky_relu(concat(x,agg) @ W + b), W is [64][outd]
__global__ __launch_bounds__(256) void k_lin(const float* __restrict__ x, const float* __restrict__ agg,
    const float* __restrict__ W, const float* __restrict__ b, float* __restrict__ out, int outd){
  int n = blockIdx.x*256 + threadIdx.x;
  if (n >= NN) return;
  int k0 = blockIdx.y * 16;
  const float* xr = x   + (size_t)n*ENCD;
  const float* ar = agg + (size_t)n*ENCD;
  float xv[32], av[32];
  #pragma unroll
  for (int q=0;q<8;q++){ float4 v = ld4(xr+4*q); xv[4*q]=v.x; xv[4*q+1]=v.y; xv[4*q+2]=v.z; xv[4*q+3]=v.w; }
  #pragma unroll
  for (int q=0;q<8;q++){ float4 v = ld4(ar+4*q); av[4*q]=v.x; av[4*q+1]=v.y; av[4*q+2]=v.z; av[4*q+3]=v.w; }
  float acc[16];
  #pragma unroll
  for (int t=0;t<16;t++) acc[t] = b[k0+t];
  #pragma unroll
  for (int j=0;j<32;j++){
    #pragma unroll
    for (int t=0;t<16;t++) acc[t] = fmaf(xv[j], W[(size_t)j*outd + k0 + t], acc[t]);
  }
  #pragma unroll
  for (int j=0;j<32;j++){
    #pragma unroll
    for (int t=0;t<16;t++) acc[t] = fmaf(av[j], W[(size_t)(32+j)*outd + k0 + t], acc[t]);
  }
  float* o = out + (size_t)n*outd + k0;
  #pragma unroll
  for (int q=0;q<4;q++){
    float4 v;
    float a0=acc[4*q],a1=acc[4*q+1],a2=acc[4*q+2],a3=acc[4*q+3];
    v.x = a0>0.f? a0 : 0.01f*a0;
    v.y = a1>0.f? a1 : 0.01f*a1;
    v.z = a2>0.f? a2 : 0.01f*a2;
    v.w = a3>0.f? a3 : 0.01f*a3;
    st4(o + 4*q, v);
  }
}

__global__ __launch_bounds__(256) void k_score(const float* __restrict__ x1, const float* __restrict__ x2,
    const int* __restrict__ users, const int* __restrict__ items, float* __restrict__ out, int Bn){
  int b = blockIdx.x*256 + threadIdx.x;
  if (b >= Bn) return;
  int u  = N_ENT + users[b];
  int it = items[b];
  const float* a1 = x1 + (size_t)u*32;
  const float* c1 = x1 + (size_t)it*32;
  const float* a2 = x2 + (size_t)u*16;
  const float* c2 = x2 + (size_t)it*16;
  float s = 0.f;
  #pragma unroll
  for (int q=0;q<8;q++){
    float4 va=ld4(a1+4*q), vb=ld4(c1+4*q);
    s = fmaf(va.x,vb.x,s); s = fmaf(va.y,vb.y,s); s = fmaf(va.z,vb.z,s); s = fmaf(va.w,vb.w,s);
  }
  #pragma unroll
  for (int q=0;q<4;q++){
    float4 va=ld4(a2+4*q), vb=ld4(c2+4*q);
    s = fmaf(va.x,vb.x,s); s = fmaf(va.y,vb.y,s); s = fmaf(va.z,vb.z,s); s = fmaf(va.w,vb.w,s);
  }
  out[b] = s;
}

extern "C" void kernel_launch(void* const* d_in, const int* in_sizes, int n_in,
                              void* d_out, int out_size, void* d_ws, size_t ws_size,
                              hipStream_t stream){
  const int*   users   = (const int*)d_in[0];
  const int*   items   = (const int*)d_in[1];
  const int*   esrc    = (const int*)d_in[2];
  const int*   edst    = (const int*)d_in[3];
  const int*   erel    = (const int*)d_in[4];
  const float* ent     = (const float*)d_in[5];
  const float* usr     = (const float*)d_in[6];
  const float* enc_W0  = (const float*)d_in[7];
  const float* enc_b0  = (const float*)d_in[8];
  const float* enc_W1  = (const float*)d_in[9];
  const float* enc_b1  = (const float*)d_in[10];
  const float* dec_W0  = (const float*)d_in[11];
  const float* dec_b0  = (const float*)d_in[12];
  const float* dec_W1  = (const float*)d_in[13];
  const float* dec_b1  = (const float*)d_in[14];
  const float* Wr1     = (const float*)d_in[15];
  const float* lin_W1  = (const float*)d_in[16];
  const float* lin_b1  = (const float*)d_in[17];
  const float* Wr2     = (const float*)d_in[18];
  const float* lin_W2  = (const float*)d_in[19];
  const float* lin_b2  = (const float*)d_in[20];
  const int E = in_sizes[2];
  const int B = in_sizes[0];

  char* wp = (char*)d_ws;
  auto carve = [&](size_t bytes)->char*{ char* p = wp; wp += (bytes + 255) & ~(size_t)255; return p; };
  float* enc    = (float*)carve((size_t)NN*32*4);
  float* x1     = (float*)carve((size_t)NN*32*4);
  float* x2     = (float*)carve((size_t)NN*16*4);
  float* agg    = (float*)carve((size_t)NN*32*4);
  float* wsum   = (float*)carve((size_t)2*RR*DD*4);
  float* dA     = (float*)carve((size_t)NN*RR*4);
  __half* dbrec = (__half*)carve((size_t)NN*RR*2);   // 32B/node src-side gate dots
  __half* xrec  = (__half*)carve((size_t)NN*32*2);   // 64B/node f16 features
  __half* gat   = (__half*)carve((size_t)E*2);       // per-edge gate stream
  int*   packed = (int*)  carve((size_t)E*4);
  unsigned* bktData = (unsigned*)carve((size_t)E*4);
  int*   bktCnt = (int*)  carve((size_t)2*NB*4);     // cnt[256] + fill[256], one memset
  int*   bktFill= bktCnt + NB;
  int*   bktBase= (int*)  carve(NB*4);
  int*   rowp   = (int*)  carve(((size_t)NN+1)*4);

  const int nbN  = (NN + 255)/256;    // 235
  const int nbT  = (E + 4095)/4096;   // 4096-edge tiles (bucketA)
  const int nbTh = (E + 8191)/8192;   // 8192-edge tiles (fused hist)
  const int nbAE = (NN + 63)/64;      // 938
  const int nbD  = (NN*RR + 255)/256;
  dim3 blk(256);

  hipMemsetAsync(d_out, 0, (size_t)out_size*sizeof(float), stream);
  hipMemsetAsync(bktCnt, 0, (size_t)2*NB*sizeof(int), stream);

  // fused AE + hist + wsum
  k_ae_hist<<<dim3(nbAE + nbTh + 4), dim3(512), 0, stream>>>(
      ent, usr, enc_W0, enc_b0, enc_W1, enc_b1, dec_W0, dec_b0, dec_W1, dec_b1,
      enc, ((float*)d_out) + B, edst, bktCnt, Wr1, Wr2, wsum, E, nbAE, nbTh);

  // CSR build via 256-bucket two-phase counting sort
  k_scan256<<<1, blk, 0, stream>>>(bktCnt, bktBase);
  k_bucketA<<<nbT, blk, 0, stream>>>(esrc, edst, erel, bktBase, bktFill, bktData, E);
  k_buildB <<<NBU, blk, 0, stream>>>(bktData, bktBase, bktCnt, rowp, packed);

  k_dots <<<nbD, blk, 0, stream>>>(enc, wsum, dA, dbrec, xrec);
  k_gates<<<NBU*4, blk, 0, stream>>>(packed, bktBase, bktCnt, dA, dbrec, gat);
  k_agg  <<<(NN+7)/8, blk, 0, stream>>>((const __half2*)xrec, packed, gat, rowp, agg);
  k_lin  <<<dim3(nbN, 2), blk, 0, stream>>>(enc, agg, lin_W1, lin_b1, x1, 32);

  k_dots <<<nbD, blk, 0, stream>>>(x1, wsum + RR*DD, dA, dbrec, xrec);
  k_gates<<<NBU*4, blk, 0, stream>>>(packed, bktBase, bktCnt, dA, dbrec, gat);
  k_agg  <<<(NN+7)/8, blk, 0, stream>>>((const __half2*)xrec, packed, gat, rowp, agg);
  k_lin  <<<dim3(nbN, 1), blk, 0, stream>>>(x1, agg, lin_W2, lin_b2, x2, 16);

  k_score<<<(B+255)/256, blk, 0, stream>>>(x1, x2, users, items, (float*)d_out, B);
}

// Round 10
// 368.055 us; speedup vs baseline: 1.0558x; 1.0558x over previous
//
#include <hip/hip_runtime.h>
#include <hip/hip_fp16.h>
#include <math.h>

#define N_ENT 50000
#define N_USR 10000
#define NN    60000
#define DD    64
#define H0    128
#define ENCD  32
#define RR    16
#define NB    256
#define BSH   8
#define NBU   235   // ceil(NN/256): buckets actually used

__device__ __forceinline__ float4 ld4(const float* p){ return *reinterpret_cast<const float4*>(p); }
__device__ __forceinline__ void st4(float* p, float4 v){ *reinterpret_cast<float4*>(p) = v; }

// Fused: [0,nbAE) = autoencoder (64 nodes/block); [nbAE,nbAE+nbTh) = edge histogram;
// [nbAE+nbTh, +4) = w_sum reduction. 512 threads everywhere.
// AE LDS: xs f32 16.6KB (coalesced-staged) + hs2 f16 16.9KB + es f32 8.3KB = 41.8KB
// -> 3 blocks/CU, 6 waves/SIMD, conflict-free layouts.
__global__ __launch_bounds__(512, 6) void k_ae_hist(const float* __restrict__ ent, const float* __restrict__ usr,
    const float* __restrict__ eW0, const float* __restrict__ eb0,
    const float* __restrict__ eW1, const float* __restrict__ eb1,
    const float* __restrict__ dW0c, const float* __restrict__ db0,
    const float* __restrict__ dW1c, const float* __restrict__ db1,
    float* __restrict__ enc, float* __restrict__ loss_out,
    const int* __restrict__ edst, int* __restrict__ bktCnt,
    const float* __restrict__ Wr1, const float* __restrict__ Wr2, float* __restrict__ wsum,
    int E_, int nbAE, int nbTh){
  __shared__ float   xs[DD][65];      // 16.6 KB
  __shared__ __half2 hs2[H0/2][66];   // 16.9 KB (h1 then h2; hs2[j>>1][n] = {h_2j, h_2j+1})
  __shared__ float   es[ENCD][65];    // 8.3 KB
  __shared__ float   sred[8];
  int bid = blockIdx.x;
  int t = threadIdx.x;

  if (bid >= nbAE){
    int rb = bid - nbAE;
    if (rb < nbTh){
      // ---- histogram branch: 8192 edges/block (xs reused as int scratch) ----
      int* hh = (int*)&xs[0][0];
      if (t < NB) hh[t] = 0;
      __syncthreads();
      int i0 = rb*8192;
      #pragma unroll
      for (int k=0;k<16;k++){
        int e = i0 + k*512 + t;
        if (e < E_) atomicAdd(&hh[((unsigned)edst[e])>>BSH], 1);
      }
      __syncthreads();
      if (t < NB){ int c = hh[t]; if (c) atomicAdd(&bktCnt[t], c); }
    } else {
      // ---- wsum branch ----
      int i = (rb - nbTh)*512 + t;
      if (i < 2*RR*DD){
        const float* Wr = (i < RR*DD) ? Wr1 : Wr2;
        int loc = i & (RR*DD - 1);
        const float* p = Wr + (size_t)loc*32;
        float s = 0.f;
        #pragma unroll
        for (int k=0;k<32;k++) s += p[k];
        wsum[i] = s;
      }
    }
    return;
  }

  // ---- AE branch ----
  int nl = t & 63;
  int wid = __builtin_amdgcn_readfirstlane(t >> 6);   // 0..7

  // stage x coalesced: thread t loads 8 floats of node (t>>3), cols (t&7)*8, transposed
  {
    int n2 = t >> 3;
    int d0 = (t & 7) * 8;
    int gn = bid*64 + n2;
    if (gn < NN){
      const float* xr = (gn < N_ENT) ? ent + (size_t)gn*DD : usr + (size_t)(gn-N_ENT)*DD;
      #pragma unroll
      for (int q=0;q<2;q++){
        float4 v = ld4(xr + d0 + 4*q);
        xs[d0+4*q+0][n2]=v.x; xs[d0+4*q+1][n2]=v.y; xs[d0+4*q+2][n2]=v.z; xs[d0+4*q+3][n2]=v.w;
      }
    } else {
      #pragma unroll
      for (int q=0;q<8;q++) xs[d0+q][n2]=0.f;
    }
  }
  __syncthreads();

  // phase1: h1[j0..j0+15] = relu(x @ eW0 + eb0), stored as f16 pairs
  {
    int j0 = wid*16;
    float acc[16];
    #pragma unroll
    for (int k=0;k<16;k++) acc[k]=eb0[j0+k];
    #pragma unroll 4
    for (int d=0;d<DD;d++){
      float x = xs[d][nl];
      const float* w = eW0 + (size_t)d*H0 + j0;
      #pragma unroll
      for (int k=0;k<16;k++) acc[k]=fmaf(x,w[k],acc[k]);
    }
    #pragma unroll
    for (int k=0;k<8;k++){
      __half2 hv;
      hv.x = __float2half(fmaxf(acc[2*k],0.f));
      hv.y = __float2half(fmaxf(acc[2*k+1],0.f));
      hs2[j0/2+k][nl] = hv;
    }
  }
  __syncthreads();

  // phase2: enc[k0..k0+3] = h1 @ eW1 + eb1  (each half2 read feeds 8 FMA)
  {
    int k0 = wid*4;
    float acc[4];
    #pragma unroll
    for (int k=0;k<4;k++) acc[k]=eb1[k0+k];
    #pragma unroll 4
    for (int jj=0;jj<H0/2;jj++){
      float2 hv = __half22float2(hs2[jj][nl]);
      const float* w0 = eW1 + (size_t)(2*jj)*ENCD + k0;
      const float* w1 = w0 + ENCD;
      #pragma unroll
      for (int k=0;k<4;k++) acc[k]=fmaf(hv.x,w0[k],acc[k]);
      #pragma unroll
      for (int k=0;k<4;k++) acc[k]=fmaf(hv.y,w1[k],acc[k]);
    }
    #pragma unroll
    for (int k=0;k<4;k++) es[k0+k][nl]=acc[k];
  }
  __syncthreads();

  // coalesced enc writeout: thread t stores 16B of node (t>>3)
  {
    int n2 = t >> 3;
    int k2 = (t & 7) * 4;
    int gn2 = bid*64 + n2;
    if (gn2 < NN){
      float4 a;
      a.x=es[k2+0][n2]; a.y=es[k2+1][n2]; a.z=es[k2+2][n2]; a.w=es[k2+3][n2];
      st4(enc + (size_t)gn2*ENCD + k2, a);
    }
  }

  // phase3: h2[j0..j0+15] = relu(enc @ dW0 + db0), stored f16 pairs
  {
    int j0 = wid*16;
    float acc[16];
    #pragma unroll
    for (int k=0;k<16;k++) acc[k]=db0[j0+k];
    #pragma unroll 4
    for (int d=0;d<ENCD;d++){
      float x = es[d][nl];
      const float* w = dW0c + (size_t)d*H0 + j0;
      #pragma unroll
      for (int k=0;k<16;k++) acc[k]=fmaf(x,w[k],acc[k]);
    }
    #pragma unroll
    for (int k=0;k<8;k++){
      __half2 hv;
      hv.x = __float2half(fmaxf(acc[2*k],0.f));
      hv.y = __float2half(fmaxf(acc[2*k+1],0.f));
      hs2[j0/2+k][nl] = hv;
    }
  }
  __syncthreads();

  // phase4: dec[c0..c0+7] = h2 @ dW1 + db1 ; loss vs xs (f32, exact)
  float part = 0.f;
  {
    int c0 = wid*8;
    float acc[8];
    #pragma unroll
    for (int k=0;k<8;k++) acc[k]=db1[c0+k];
    #pragma unroll 4
    for (int jj=0;jj<H0/2;jj++){
      float2 hv = __half22float2(hs2[jj][nl]);
      const float* w0 = dW1c + (size_t)(2*jj)*DD + c0;
      const float* w1 = w0 + DD;
      #pragma unroll
      for (int k=0;k<8;k++) acc[k]=fmaf(hv.x,w0[k],acc[k]);
      #pragma unroll
      for (int k=0;k<8;k++) acc[k]=fmaf(hv.y,w1[k],acc[k]);
    }
    int gnode = bid*64 + nl;
    if (gnode < NN){
      #pragma unroll
      for (int k=0;k<8;k++){ float d_ = acc[k]-xs[c0+k][nl]; part = fmaf(d_,d_,part); }
    }
  }
  #pragma unroll
  for (int off=32; off>0; off>>=1) part += __shfl_down(part, off, 64);
  if ((t&63)==0) sred[wid] = part;
  __syncthreads();
  if (t==0){
    float s = 0.f;
    #pragma unroll
    for (int k=0;k<8;k++) s += sred[k];
    atomicAdd(loss_out, s * (1.0f/((float)NN*(float)DD)));
  }
}

// bucketed append with internal bucket-base scan: each block reserves exclusive chunks
__global__ __launch_bounds__(256) void k_bucketA(const int* __restrict__ esrc, const int* __restrict__ edst,
    const int* __restrict__ erel, const int* __restrict__ bktCnt, int* __restrict__ bktFill,
    unsigned* __restrict__ bktData, int E_){
  __shared__ int h[NB];
  __shared__ int gbase[NB];
  __shared__ int wps[4];
  int t = threadIdx.x;
  // exclusive scan of bktCnt (256 entries) -> sb
  int cv = bktCnt[t];
  int cx = cv;
  #pragma unroll
  for (int off=1; off<64; off<<=1){ int y=__shfl_up(cx,off,64); if ((t&63)>=off) cx+=y; }
  if ((t&63)==63) wps[t>>6] = cx;
  __syncthreads();
  if (t<4){
    int wv=wps[t]; int wx=wv;
    #pragma unroll
    for (int off=1; off<4; off<<=1){ int y=__shfl_up(wx,off,4); if (t>=off) wx+=y; }
    wps[t]=wx-wv;
  }
  __syncthreads();
  int sb = (cx - cv) + wps[t>>6];
  h[t]=0;
  __syncthreads();
  int i0 = blockIdx.x*4096;
  int dcache[16];
  #pragma unroll
  for (int k=0;k<16;k++){
    int e = i0 + k*256 + t;
    int d = (e < E_) ? edst[e] : -1;
    dcache[k] = d;
    if (d >= 0) atomicAdd(&h[((unsigned)d)>>BSH], 1);
  }
  __syncthreads();
  {
    int c = h[t];
    int off = c ? atomicAdd(&bktFill[t], c) : 0;
    gbase[t] = sb + off;
    h[t] = 0;   // reuse as local fill
  }
  __syncthreads();
  #pragma unroll
  for (int k=0;k<16;k++){
    int e = i0 + k*256 + t;
    if (e >= E_) continue;
    int d = dcache[k];
    int b = ((unsigned)d) >> BSH;
    int slot = atomicAdd(&h[b], 1);
    unsigned rec = (unsigned)esrc[e] | ((unsigned)erel[e] << 16) | ((unsigned)(d & 0xFF) << 20);
    bktData[(size_t)gbase[b] + slot] = rec;
  }
}

// per-bucket CSR build with internal bucket-base scan
__global__ __launch_bounds__(256) void k_buildB(const unsigned* __restrict__ bktData,
    const int* __restrict__ bktCnt, int* __restrict__ rowp, int* __restrict__ packed){
  __shared__ int cnt[NB];
  __shared__ int start[NB];
  __shared__ int wps[4];
  int b = blockIdx.x;
  int t = threadIdx.x;
  // exclusive scan of bktCnt -> base for bucket b
  int cv = bktCnt[t];
  int cx = cv;
  #pragma unroll
  for (int off=1; off<64; off<<=1){ int y=__shfl_up(cx,off,64); if ((t&63)>=off) cx+=y; }
  if ((t&63)==63) wps[t>>6] = cx;
  __syncthreads();
  if (t<4){
    int wv=wps[t]; int wx=wv;
    #pragma unroll
    for (int off=1; off<4; off<<=1){ int y=__shfl_up(wx,off,4); if (t>=off) wx+=y; }
    wps[t]=wx-wv;
  }
  __syncthreads();
  cnt[t] = (cx - cv) + wps[t>>6];   // stash exclusive scan in cnt temporarily
  __syncthreads();
  int base = cnt[b];
  int n = bktCnt[b];
  __syncthreads();
  cnt[t] = 0;
  __syncthreads();
  for (int i=t; i<n; i+=256) atomicAdd(&cnt[(bktData[(size_t)base+i] >> 20) & 0xFF], 1);
  __syncthreads();
  int v = cnt[t];
  cnt[t] = 0;                       // reset for fill pass
  int x = v;
  #pragma unroll
  for (int off=1; off<64; off<<=1){ int y=__shfl_up(x,off,64); if ((t&63)>=off) x+=y; }
  if ((t&63)==63) wps[t>>6] = x;
  __syncthreads();
  if (t<4){
    int wv=wps[t]; int wx=wv;
    #pragma unroll
    for (int off=1; off<4; off<<=1){ int y=__shfl_up(wx,off,4); if (t>=off) wx+=y; }
    wps[t]=wx-wv;
  }
  __syncthreads();
  int sv = (x - v) + wps[t>>6];     // exclusive prefix over dl
  start[t] = sv;
  int node = (b << BSH) + t;
  if (node <= NN) rowp[node] = base + sv;
  __syncthreads();
  for (int i=t; i<n; i+=256){
    unsigned r = bktData[(size_t)base+i];
    int dl = (r >> 20) & 0xFF;
    int p = start[dl] + atomicAdd(&cnt[dl], 1);
    packed[(size_t)base + p] = (int)r;      // keep src|rel|dl
  }
}

// Per-node per-relation gate partials + f16 tables
__global__ __launch_bounds__(256) void k_dots(const float* __restrict__ x, const float* __restrict__ wsum,
    float* __restrict__ dA, __half* __restrict__ dbrec, __half* __restrict__ xrec){
  __shared__ float wl[RR*DD];                  // wl[j*16+rel] = wsum[rel*64+j]
  for (int i = threadIdx.x; i < RR*DD; i += 256){
    int r = i & 15; int j = i >> 4;
    wl[i] = wsum[r*DD + j];
  }
  __syncthreads();
  int t = blockIdx.x*256 + threadIdx.x;
  if (t >= NN*RR) return;
  int n = t >> 4, r = t & 15;
  const float* xr = x + (size_t)n*ENCD;
  float a = 0.f, b = 0.f;
  float xlo = 0.f, xhi = 0.f;
  #pragma unroll
  for (int q=0;q<8;q++){
    float4 v = ld4(xr + 4*q);
    int j = 4*q;
    if (r >= j && r < j+4){ float tmp[4]={v.x,v.y,v.z,v.w}; xlo = tmp[r-j]; }
    if (r+16 >= j && r+16 < j+4){ float tmp[4]={v.x,v.y,v.z,v.w}; xhi = tmp[r+16-j]; }
    a = fmaf(v.x, wl[(j+0)*16 + r], a);
    a = fmaf(v.y, wl[(j+1)*16 + r], a);
    a = fmaf(v.z, wl[(j+2)*16 + r], a);
    a = fmaf(v.w, wl[(j+3)*16 + r], a);
    b = fmaf(v.x, wl[(32+j+0)*16 + r], b);
    b = fmaf(v.y, wl[(32+j+1)*16 + r], b);
    b = fmaf(v.z, wl[(32+j+2)*16 + r], b);
    b = fmaf(v.w, wl[(32+j+3)*16 + r], b);
  }
  dA[t] = a;
  dbrec[t] = __float2half(b);
  xrec[(size_t)n*32 + r]      = __float2half(xlo);
  xrec[(size_t)n*32 + 16 + r] = __float2half(xhi);
}

// Per-edge gate pass: sequential packed stream, L2-resident dbrec gather, f16 gate stream out
__global__ __launch_bounds__(256) void k_gates(const int* __restrict__ packed,
    const int* __restrict__ bktBaseCnt, const int* __restrict__ bktCnt,
    const float* __restrict__ dA, const __half* __restrict__ dbrec, __half* __restrict__ gat){
  // bktBaseCnt: recompute base from scan-free trick: bases stored in rowp? Instead pass rowp-derived:
  // here bktBaseCnt = rowp (rowp[(b<<BSH)] is the base of bucket b since dl=0 prefix is 0)
  int b = blockIdx.x >> 2, g = blockIdx.x & 3;
  int base = bktBaseCnt[b << BSH];       // rowp[bucket start node] == bucket base
  int n = bktCnt[b];
  int lo = (n*g) >> 2, hi = (n*(g+1)) >> 2;
  #pragma unroll 2
  for (int i = lo + (int)threadIdx.x; i < hi; i += 256){
    int p = packed[(size_t)base+i];
    int s = p & 0xFFFF;
    int r = (p >> 16) & 15;
    int dl = (p >> 20) & 0xFF;
    int dst = (b << BSH) | dl;
    float z = dA[dst*16 + r] + __half2float(dbrec[s*16 + r]);
    gat[(size_t)base+i] = __float2half(1.f/(1.f + __expf(-z)));
  }
}

// Scatter-mean via CSR gather: 16 lanes/node, 4-deep software pipeline for MLP
__global__ __launch_bounds__(256) void k_agg(const __half2* __restrict__ xrec2, const int* __restrict__ packed,
    const __half* __restrict__ gat, const int* __restrict__ rowp, float* __restrict__ agg){
  int node = blockIdx.x*16 + (threadIdx.x >> 4);
  int l = threadIdx.x & 15;
  if (node >= NN) return;
  int beg = rowp[node], end = rowp[node+1];
  float ax = 0.f, ay = 0.f;
  int i = beg;
  for (; i + 4 <= end; i += 4){
    int p0 = packed[i], p1 = packed[i+1], p2 = packed[i+2], p3 = packed[i+3];
    float g0 = __half2float(gat[i]);
    float g1 = __half2float(gat[i+1]);
    float g2 = __half2float(gat[i+2]);
    float g3 = __half2float(gat[i+3]);
    float2 f0 = __half22float2(xrec2[(size_t)(p0 & 0xFFFF)*16 + l]);
    float2 f1 = __half22float2(xrec2[(size_t)(p1 & 0xFFFF)*16 + l]);
    float2 f2 = __half22float2(xrec2[(size_t)(p2 & 0xFFFF)*16 + l]);
    float2 f3 = __half22float2(xrec2[(size_t)(p3 & 0xFFFF)*16 + l]);
    ax = fmaf(f0.x, g0, ax); ay = fmaf(f0.y, g0, ay);
    ax = fmaf(f1.x, g1, ax); ay = fmaf(f1.y, g1, ay);
    ax = fmaf(f2.x, g2, ax); ay = fmaf(f2.y, g2, ay);
    ax = fmaf(f3.x, g3, ax); ay = fmaf(f3.y, g3, ay);
  }
  for (; i < end; i++){
    int p = packed[i];
    float g = __half2float(gat[i]);
    float2 fx = __half22float2(xrec2[(size_t)(p & 0xFFFF)*16 + l]);
    ax = fmaf(fx.x, g, ax); ay = fmaf(fx.y, g, ay);
  }
  int deg = end - beg;
  float inv = (deg > 0) ? 1.f/(float)deg : 0.f;
  float2 o; o.x = ax*inv; o.y = ay*inv;
  *reinterpret_cast<float2*>(&agg[(size_t)node*ENCD + 2*l]) = o;
}

// out = leaky_relu(concat(x,agg) @ W + b), W is [64][outd]
__global__ __launch_bounds__(256) void k_lin(const float* __restrict__ x, const float* __restrict__ agg,
    const float* __restrict__ W, const float* __restrict__ b, float* __restrict__ out, int outd){
  int n = blockIdx.x*256 + threadIdx.x;
  if (n >= NN) return;
  int k0 = blockIdx.y * 16;
  const float* xr = x   + (size_t)n*ENCD;
  const float* ar = agg + (size_t)n*ENCD;
  float xv[32], av[32];
  #pragma unroll
  for (int q=0;q<8;q++){ float4 v = ld4(xr+4*q); xv[4*q]=v.x; xv[4*q+1]=v.y; xv[4*q+2]=v.z; xv[4*q+3]=v.w; }
  #pragma unroll
  for (int q=0;q<8;q++){ float4 v = ld4(ar+4*q); av[4*q]=v.x; av[4*q+1]=v.y; av[4*q+2]=v.z; av[4*q+3]=v.w; }
  float acc[16];
  #pragma unroll
  for (int t=0;t<16;t++) acc[t] = b[k0+t];
  #pragma unroll
  for (int j=0;j<32;j++){
    #pragma unroll
    for (int t=0;t<16;t++) acc[t] = fmaf(xv[j], W[(size_t)j*outd + k0 + t], acc[t]);
  }
  #pragma unroll
  for (int j=0;j<32;j++){
    #pragma unroll
    for (int t=0;t<16;t++) acc[t] = fmaf(av[j], W[(size_t)(32+j)*outd + k0 + t], acc[t]);
  }
  float* o = out + (size_t)n*outd + k0;
  #pragma unroll
  for (int q=0;q<4;q++){
    float4 v;
    float a0=acc[4*q],a1=acc[4*q+1],a2=acc[4*q+2],a3=acc[4*q+3];
    v.x = a0>0.f? a0 : 0.01f*a0;
    v.y = a1>0.f? a1 : 0.01f*a1;
    v.z = a2>0.f? a2 : 0.01f*a2;
    v.w = a3>0.f? a3 : 0.01f*a3;
    st4(o + 4*q, v);
  }
}

__global__ __launch_bounds__(256) void k_score(const float* __restrict__ x1, const float* __restrict__ x2,
    const int* __restrict__ users, const int* __restrict__ items, float* __restrict__ out, int Bn){
  int b = blockIdx.x*256 + threadIdx.x;
  if (b >= Bn) return;
  int u  = N_ENT + users[b];
  int it = items[b];
  const float* a1 = x1 + (size_t)u*32;
  const float* c1 = x1 + (size_t)it*32;
  const float* a2 = x2 + (size_t)u*16;
  const float* c2 = x2 + (size_t)it*16;
  float s = 0.f;
  #pragma unroll
  for (int q=0;q<8;q++){
    float4 va=ld4(a1+4*q), vb=ld4(c1+4*q);
    s = fmaf(va.x,vb.x,s); s = fmaf(va.y,vb.y,s); s = fmaf(va.z,vb.z,s); s = fmaf(va.w,vb.w,s);
  }
  #pragma unroll
  for (int q=0;q<4;q++){
    float4 va=ld4(a2+4*q), vb=ld4(c2+4*q);
    s = fmaf(va.x,vb.x,s); s = fmaf(va.y,vb.y,s); s = fmaf(va.z,vb.z,s); s = fmaf(va.w,vb.w,s);
  }
  out[b] = s;
}

extern "C" void kernel_launch(void* const* d_in, const int* in_sizes, int n_in,
                              void* d_out, int out_size, void* d_ws, size_t ws_size,
                              hipStream_t stream){
  const int*   users   = (const int*)d_in[0];
  const int*   items   = (const int*)d_in[1];
  const int*   esrc    = (const int*)d_in[2];
  const int*   edst    = (const int*)d_in[3];
  const int*   erel    = (const int*)d_in[4];
  const float* ent     = (const float*)d_in[5];
  const float* usr     = (const float*)d_in[6];
  const float* enc_W0  = (const float*)d_in[7];
  const float* enc_b0  = (const float*)d_in[8];
  const float* enc_W1  = (const float*)d_in[9];
  const float* enc_b1  = (const float*)d_in[10];
  const float* dec_W0  = (const float*)d_in[11];
  const float* dec_b0  = (const float*)d_in[12];
  const float* dec_W1  = (const float*)d_in[13];
  const float* dec_b1  = (const float*)d_in[14];
  const float* Wr1     = (const float*)d_in[15];
  const float* lin_W1  = (const float*)d_in[16];
  const float* lin_b1  = (const float*)d_in[17];
  const float* Wr2     = (const float*)d_in[18];
  const float* lin_W2  = (const float*)d_in[19];
  const float* lin_b2  = (const float*)d_in[20];
  const int E = in_sizes[2];
  const int B = in_sizes[0];

  char* wp = (char*)d_ws;
  auto carve = [&](size_t bytes)->char*{ char* p = wp; wp += (bytes + 255) & ~(size_t)255; return p; };
  float* enc    = (float*)carve((size_t)NN*32*4);
  float* x1     = (float*)carve((size_t)NN*32*4);
  float* x2     = (float*)carve((size_t)NN*16*4);
  float* agg    = (float*)carve((size_t)NN*32*4);
  float* wsum   = (float*)carve((size_t)2*RR*DD*4);
  float* dA     = (float*)carve((size_t)NN*RR*4);
  __half* dbrec = (__half*)carve((size_t)NN*RR*2);   // 32B/node src-side gate dots
  __half* xrec  = (__half*)carve((size_t)NN*32*2);   // 64B/node f16 features
  __half* gat   = (__half*)carve((size_t)E*2);       // per-edge gate stream
  int*   packed = (int*)  carve((size_t)E*4);
  unsigned* bktData = (unsigned*)carve((size_t)E*4);
  int*   bktCnt = (int*)  carve((size_t)2*NB*4);     // cnt[256] + fill[256], one memset
  int*   bktFill= bktCnt + NB;
  int*   rowp   = (int*)  carve(((size_t)NN+256)*4);

  const int nbN  = (NN + 255)/256;    // 235
  const int nbT  = (E + 4095)/4096;   // 4096-edge tiles (bucketA)
  const int nbTh = (E + 8191)/8192;   // 8192-edge tiles (fused hist)
  const int nbAE = (NN + 63)/64;      // 938
  const int nbD  = (NN*RR + 255)/256;
  dim3 blk(256);

  hipMemsetAsync(d_out, 0, (size_t)out_size*sizeof(float), stream);
  hipMemsetAsync(bktCnt, 0, (size_t)2*NB*sizeof(int), stream);

  // fused AE + hist + wsum
  k_ae_hist<<<dim3(nbAE + nbTh + 4), dim3(512), 0, stream>>>(
      ent, usr, enc_W0, enc_b0, enc_W1, enc_b1, dec_W0, dec_b0, dec_W1, dec_b1,
      enc, ((float*)d_out) + B, edst, bktCnt, Wr1, Wr2, wsum, E, nbAE, nbTh);

  // CSR build via 256-bucket two-phase counting sort (scan folded into both kernels)
  k_bucketA<<<nbT, blk, 0, stream>>>(esrc, edst, erel, bktCnt, bktFill, bktData, E);
  k_buildB <<<NBU, blk, 0, stream>>>(bktData, bktCnt, rowp, packed);

  k_dots <<<nbD, blk, 0, stream>>>(enc, wsum, dA, dbrec, xrec);
  k_gates<<<NBU*4, blk, 0, stream>>>(packed, rowp, bktCnt, dA, dbrec, gat);
  k_agg  <<<(NN+15)/16, blk, 0, stream>>>((const __half2*)xrec, packed, gat, rowp, agg);
  k_lin  <<<dim3(nbN, 2), blk, 0, stream>>>(enc, agg, lin_W1, lin_b1, x1, 32);

  k_dots <<<nbD, blk, 0, stream>>>(x1, wsum + RR*DD, dA, dbrec, xrec);
  k_gates<<<NBU*4, blk, 0, stream>>>(packed, rowp, bktCnt, dA, dbrec, gat);
  k_agg  <<<(NN+15)/16, blk, 0, stream>>>((const __half2*)xrec, packed, gat, rowp, agg);
  k_lin  <<<dim3(nbN, 1), blk, 0, stream>>>(x1, agg, lin_W2, lin_b2, x2, 16);

  k_score<<<(B+255)/256, blk, 0, stream>>>(x1, x2, users, items, (float*)d_out, B);
}

// Round 11
// 366.001 us; speedup vs baseline: 1.0617x; 1.0056x over previous
//
#include <hip/hip_runtime.h>
#include <hip/hip_fp16.h>
#include <math.h>

#define N_ENT 50000
#define N_USR 10000
#define NN    60000
#define DD    64
#define H0    128
#define ENCD  32
#define RR    16
#define NB    256
#define BSH   8
#define NBU   235   // ceil(NN/256): buckets actually used

__device__ __forceinline__ float4 ld4(const float* p){ return *reinterpret_cast<const float4*>(p); }
__device__ __forceinline__ void st4(float* p, float4 v){ *reinterpret_cast<float4*>(p) = v; }

// Fused: [0,nbAE) = autoencoder (64 nodes/block); [nbAE,nbAE+nbTh) = edge histogram;
// [nbAE+nbTh, +4) = w_sum reduction. 512 threads everywhere.
// AE LDS: xs f32 16.6KB (coalesced-staged) + hs2 f16 16.9KB + es f32 8.3KB = 41.8KB
// -> 3 blocks/CU, 6 waves/SIMD, conflict-free layouts.
__global__ __launch_bounds__(512, 6) void k_ae_hist(const float* __restrict__ ent, const float* __restrict__ usr,
    const float* __restrict__ eW0, const float* __restrict__ eb0,
    const float* __restrict__ eW1, const float* __restrict__ eb1,
    const float* __restrict__ dW0c, const float* __restrict__ db0,
    const float* __restrict__ dW1c, const float* __restrict__ db1,
    float* __restrict__ enc, float* __restrict__ loss_out,
    const int* __restrict__ edst, int* __restrict__ bktCnt,
    const float* __restrict__ Wr1, const float* __restrict__ Wr2, float* __restrict__ wsum,
    int E_, int nbAE, int nbTh){
  __shared__ float   xs[DD][65];      // 16.6 KB
  __shared__ __half2 hs2[H0/2][66];   // 16.9 KB (h1 then h2; hs2[j>>1][n] = {h_2j, h_2j+1})
  __shared__ float   es[ENCD][65];    // 8.3 KB
  __shared__ float   sred[8];
  int bid = blockIdx.x;
  int t = threadIdx.x;

  if (bid >= nbAE){
    int rb = bid - nbAE;
    if (rb < nbTh){
      // ---- histogram branch: 8192 edges/block (xs reused as int scratch) ----
      int* hh = (int*)&xs[0][0];
      if (t < NB) hh[t] = 0;
      __syncthreads();
      int i0 = rb*8192;
      #pragma unroll
      for (int k=0;k<16;k++){
        int e = i0 + k*512 + t;
        if (e < E_) atomicAdd(&hh[((unsigned)edst[e])>>BSH], 1);
      }
      __syncthreads();
      if (t < NB){ int c = hh[t]; if (c) atomicAdd(&bktCnt[t], c); }
    } else {
      // ---- wsum branch ----
      int i = (rb - nbTh)*512 + t;
      if (i < 2*RR*DD){
        const float* Wr = (i < RR*DD) ? Wr1 : Wr2;
        int loc = i & (RR*DD - 1);
        const float* p = Wr + (size_t)loc*32;
        float s = 0.f;
        #pragma unroll
        for (int k=0;k<32;k++) s += p[k];
        wsum[i] = s;
      }
    }
    return;
  }

  // ---- AE branch ----
  int nl = t & 63;
  int wid = __builtin_amdgcn_readfirstlane(t >> 6);   // 0..7

  // stage x coalesced: thread t loads 8 floats of node (t>>3), cols (t&7)*8, transposed
  {
    int n2 = t >> 3;
    int d0 = (t & 7) * 8;
    int gn = bid*64 + n2;
    if (gn < NN){
      const float* xr = (gn < N_ENT) ? ent + (size_t)gn*DD : usr + (size_t)(gn-N_ENT)*DD;
      #pragma unroll
      for (int q=0;q<2;q++){
        float4 v = ld4(xr + d0 + 4*q);
        xs[d0+4*q+0][n2]=v.x; xs[d0+4*q+1][n2]=v.y; xs[d0+4*q+2][n2]=v.z; xs[d0+4*q+3][n2]=v.w;
      }
    } else {
      #pragma unroll
      for (int q=0;q<8;q++) xs[d0+q][n2]=0.f;
    }
  }
  __syncthreads();

  // phase1: h1[j0..j0+15] = relu(x @ eW0 + eb0), stored as f16 pairs
  {
    int j0 = wid*16;
    float acc[16];
    #pragma unroll
    for (int k=0;k<16;k++) acc[k]=eb0[j0+k];
    #pragma unroll 4
    for (int d=0;d<DD;d++){
      float x = xs[d][nl];
      const float* w = eW0 + (size_t)d*H0 + j0;
      #pragma unroll
      for (int k=0;k<16;k++) acc[k]=fmaf(x,w[k],acc[k]);
    }
    #pragma unroll
    for (int k=0;k<8;k++){
      __half2 hv;
      hv.x = __float2half(fmaxf(acc[2*k],0.f));
      hv.y = __float2half(fmaxf(acc[2*k+1],0.f));
      hs2[j0/2+k][nl] = hv;
    }
  }
  __syncthreads();

  // phase2: enc[k0..k0+3] = h1 @ eW1 + eb1  (each half2 read feeds 8 FMA)
  {
    int k0 = wid*4;
    float acc[4];
    #pragma unroll
    for (int k=0;k<4;k++) acc[k]=eb1[k0+k];
    #pragma unroll 4
    for (int jj=0;jj<H0/2;jj++){
      float2 hv = __half22float2(hs2[jj][nl]);
      const float* w0 = eW1 + (size_t)(2*jj)*ENCD + k0;
      const float* w1 = w0 + ENCD;
      #pragma unroll
      for (int k=0;k<4;k++) acc[k]=fmaf(hv.x,w0[k],acc[k]);
      #pragma unroll
      for (int k=0;k<4;k++) acc[k]=fmaf(hv.y,w1[k],acc[k]);
    }
    #pragma unroll
    for (int k=0;k<4;k++) es[k0+k][nl]=acc[k];
  }
  __syncthreads();

  // coalesced enc writeout: thread t stores 16B of node (t>>3)
  {
    int n2 = t >> 3;
    int k2 = (t & 7) * 4;
    int gn2 = bid*64 + n2;
    if (gn2 < NN){
      float4 a;
      a.x=es[k2+0][n2]; a.y=es[k2+1][n2]; a.z=es[k2+2][n2]; a.w=es[k2+3][n2];
      st4(enc + (size_t)gn2*ENCD + k2, a);
    }
  }

  // phase3: h2[j0..j0+15] = relu(enc @ dW0 + db0), stored f16 pairs
  {
    int j0 = wid*16;
    float acc[16];
    #pragma unroll
    for (int k=0;k<16;k++) acc[k]=db0[j0+k];
    #pragma unroll 4
    for (int d=0;d<ENCD;d++){
      float x = es[d][nl];
      const float* w = dW0c + (size_t)d*H0 + j0;
      #pragma unroll
      for (int k=0;k<16;k++) acc[k]=fmaf(x,w[k],acc[k]);
    }
    #pragma unroll
    for (int k=0;k<8;k++){
      __half2 hv;
      hv.x = __float2half(fmaxf(acc[2*k],0.f));
      hv.y = __float2half(fmaxf(acc[2*k+1],0.f));
      hs2[j0/2+k][nl] = hv;
    }
  }
  __syncthreads();

  // phase4: dec[c0..c0+7] = h2 @ dW1 + db1 ; loss vs xs (f32, exact)
  float part = 0.f;
  {
    int c0 = wid*8;
    float acc[8];
    #pragma unroll
    for (int k=0;k<8;k++) acc[k]=db1[c0+k];
    #pragma unroll 4
    for (int jj=0;jj<H0/2;jj++){
      float2 hv = __half22float2(hs2[jj][nl]);
      const float* w0 = dW1c + (size_t)(2*jj)*DD + c0;
      const float* w1 = w0 + DD;
      #pragma unroll
      for (int k=0;k<8;k++) acc[k]=fmaf(hv.x,w0[k],acc[k]);
      #pragma unroll
      for (int k=0;k<8;k++) acc[k]=fmaf(hv.y,w1[k],acc[k]);
    }
    int gnode = bid*64 + nl;
    if (gnode < NN){
      #pragma unroll
      for (int k=0;k<8;k++){ float d_ = acc[k]-xs[c0+k][nl]; part = fmaf(d_,d_,part); }
    }
  }
  #pragma unroll
  for (int off=32; off>0; off>>=1) part += __shfl_down(part, off, 64);
  if ((t&63)==0) sred[wid] = part;
  __syncthreads();
  if (t==0){
    float s = 0.f;
    #pragma unroll
    for (int k=0;k<8;k++) s += sred[k];
    atomicAdd(loss_out, s * (1.0f/((float)NN*(float)DD)));
  }
}

// bucketed append with internal bucket-base scan: each block reserves exclusive chunks
__global__ __launch_bounds__(256) void k_bucketA(const int* __restrict__ esrc, const int* __restrict__ edst,
    const int* __restrict__ erel, const int* __restrict__ bktCnt, int* __restrict__ bktFill,
    unsigned* __restrict__ bktData, int E_){
  __shared__ int h[NB];
  __shared__ int gbase[NB];
  __shared__ int wps[4];
  int t = threadIdx.x;
  // exclusive scan of bktCnt (256 entries) -> sb
  int cv = bktCnt[t];
  int cx = cv;
  #pragma unroll
  for (int off=1; off<64; off<<=1){ int y=__shfl_up(cx,off,64); if ((t&63)>=off) cx+=y; }
  if ((t&63)==63) wps[t>>6] = cx;
  __syncthreads();
  if (t<4){
    int wv=wps[t]; int wx=wv;
    #pragma unroll
    for (int off=1; off<4; off<<=1){ int y=__shfl_up(wx,off,4); if (t>=off) wx+=y; }
    wps[t]=wx-wv;
  }
  __syncthreads();
  int sb = (cx - cv) + wps[t>>6];
  h[t]=0;
  __syncthreads();
  int i0 = blockIdx.x*4096;
  int dcache[16];
  #pragma unroll
  for (int k=0;k<16;k++){
    int e = i0 + k*256 + t;
    int d = (e < E_) ? edst[e] : -1;
    dcache[k] = d;
    if (d >= 0) atomicAdd(&h[((unsigned)d)>>BSH], 1);
  }
  __syncthreads();
  {
    int c = h[t];
    int off = c ? atomicAdd(&bktFill[t], c) : 0;
    gbase[t] = sb + off;
    h[t] = 0;   // reuse as local fill
  }
  __syncthreads();
  #pragma unroll
  for (int k=0;k<16;k++){
    int e = i0 + k*256 + t;
    if (e >= E_) continue;
    int d = dcache[k];
    int b = ((unsigned)d) >> BSH;
    int slot = atomicAdd(&h[b], 1);
    unsigned rec = (unsigned)esrc[e] | ((unsigned)erel[e] << 16) | ((unsigned)(d & 0xFF) << 20);
    bktData[(size_t)gbase[b] + slot] = rec;
  }
}

// per-bucket CSR build with internal bucket-base scan
__global__ __launch_bounds__(256) void k_buildB(const unsigned* __restrict__ bktData,
    const int* __restrict__ bktCnt, int* __restrict__ rowp, int* __restrict__ packed){
  __shared__ int cnt[NB];
  __shared__ int start[NB];
  __shared__ int wps[4];
  int b = blockIdx.x;
  int t = threadIdx.x;
  // exclusive scan of bktCnt -> base for bucket b
  int cv = bktCnt[t];
  int cx = cv;
  #pragma unroll
  for (int off=1; off<64; off<<=1){ int y=__shfl_up(cx,off,64); if ((t&63)>=off) cx+=y; }
  if ((t&63)==63) wps[t>>6] = cx;
  __syncthreads();
  if (t<4){
    int wv=wps[t]; int wx=wv;
    #pragma unroll
    for (int off=1; off<4; off<<=1){ int y=__shfl_up(wx,off,4); if (t>=off) wx+=y; }
    wps[t]=wx-wv;
  }
  __syncthreads();
  cnt[t] = (cx - cv) + wps[t>>6];   // stash exclusive scan in cnt temporarily
  __syncthreads();
  int base = cnt[b];
  int n = bktCnt[b];
  __syncthreads();
  cnt[t] = 0;
  __syncthreads();
  for (int i=t; i<n; i+=256) atomicAdd(&cnt[(bktData[(size_t)base+i] >> 20) & 0xFF], 1);
  __syncthreads();
  int v = cnt[t];
  cnt[t] = 0;                       // reset for fill pass
  int x = v;
  #pragma unroll
  for (int off=1; off<64; off<<=1){ int y=__shfl_up(x,off,64); if ((t&63)>=off) x+=y; }
  if ((t&63)==63) wps[t>>6] = x;
  __syncthreads();
  if (t<4){
    int wv=wps[t]; int wx=wv;
    #pragma unroll
    for (int off=1; off<4; off<<=1){ int y=__shfl_up(wx,off,4); if (t>=off) wx+=y; }
    wps[t]=wx-wv;
  }
  __syncthreads();
  int sv = (x - v) + wps[t>>6];     // exclusive prefix over dl
  start[t] = sv;
  int node = (b << BSH) + t;
  if (node <= NN) rowp[node] = base + sv;
  __syncthreads();
  for (int i=t; i<n; i+=256){
    unsigned r = bktData[(size_t)base+i];
    int dl = (r >> 20) & 0xFF;
    int p = start[dl] + atomicAdd(&cnt[dl], 1);
    packed[(size_t)base + p] = (int)r;      // keep src|rel|dl
  }
}

// Per-node per-relation gate partials + f16 tables
__global__ __launch_bounds__(256) void k_dots(const float* __restrict__ x, const float* __restrict__ wsum,
    float* __restrict__ dA, __half* __restrict__ dbrec, __half* __restrict__ xrec){
  __shared__ float wl[RR*DD];                  // wl[j*16+rel] = wsum[rel*64+j]
  for (int i = threadIdx.x; i < RR*DD; i += 256){
    int r = i & 15; int j = i >> 4;
    wl[i] = wsum[r*DD + j];
  }
  __syncthreads();
  int t = blockIdx.x*256 + threadIdx.x;
  if (t >= NN*RR) return;
  int n = t >> 4, r = t & 15;
  const float* xr = x + (size_t)n*ENCD;
  float a = 0.f, b = 0.f;
  float xlo = 0.f, xhi = 0.f;
  #pragma unroll
  for (int q=0;q<8;q++){
    float4 v = ld4(xr + 4*q);
    int j = 4*q;
    if (r >= j && r < j+4){ float tmp[4]={v.x,v.y,v.z,v.w}; xlo = tmp[r-j]; }
    if (r+16 >= j && r+16 < j+4){ float tmp[4]={v.x,v.y,v.z,v.w}; xhi = tmp[r+16-j]; }
    a = fmaf(v.x, wl[(j+0)*16 + r], a);
    a = fmaf(v.y, wl[(j+1)*16 + r], a);
    a = fmaf(v.z, wl[(j+2)*16 + r], a);
    a = fmaf(v.w, wl[(j+3)*16 + r], a);
    b = fmaf(v.x, wl[(32+j+0)*16 + r], b);
    b = fmaf(v.y, wl[(32+j+1)*16 + r], b);
    b = fmaf(v.z, wl[(32+j+2)*16 + r], b);
    b = fmaf(v.w, wl[(32+j+3)*16 + r], b);
  }
  dA[t] = a;
  dbrec[t] = __float2half(b);
  xrec[(size_t)n*32 + r]      = __float2half(xlo);
  xrec[(size_t)n*32 + 16 + r] = __float2half(xhi);
}

// Per-edge gate pass: sequential packed stream, L2-resident dbrec gather, f16 gate stream out
__global__ __launch_bounds__(256) void k_gates(const int* __restrict__ packed,
    const int* __restrict__ rowp, const int* __restrict__ bktCnt,
    const float* __restrict__ dA, const __half* __restrict__ dbrec, __half* __restrict__ gat){
  int b = blockIdx.x >> 2, g = blockIdx.x & 3;
  int base = rowp[b << BSH];       // rowp[bucket start node] == bucket base
  int n = bktCnt[b];
  int lo = (n*g) >> 2, hi = (n*(g+1)) >> 2;
  #pragma unroll 2
  for (int i = lo + (int)threadIdx.x; i < hi; i += 256){
    int p = packed[(size_t)base+i];
    int s = p & 0xFFFF;
    int r = (p >> 16) & 15;
    int dl = (p >> 20) & 0xFF;
    int dst = (b << BSH) | dl;
    float z = dA[dst*16 + r] + __half2float(dbrec[s*16 + r]);
    gat[(size_t)base+i] = __float2half(1.f/(1.f + __expf(-z)));
  }
}

// Fused scatter-mean + linear: 16 lanes/node, 4-deep gather pipeline, then
// out = leaky_relu(concat(x,agg) @ W + b) computed in-block (W L1-resident).
__global__ __launch_bounds__(256) void k_aggl(const __half2* __restrict__ xrec2, const int* __restrict__ packed,
    const __half* __restrict__ gat, const int* __restrict__ rowp, const float* __restrict__ x,
    const float* __restrict__ W, const float* __restrict__ bias, float* __restrict__ out, int outd){
  __shared__ float aggs[16][33];
  __shared__ float xss[16][33];
  int t = threadIdx.x;
  int node = blockIdx.x*16 + (t >> 4);
  int l = t & 15;
  int n2 = t >> 4;
  if (node >= NN) return;
  int beg = rowp[node], end = rowp[node+1];
  float ax = 0.f, ay = 0.f;
  int i = beg;
  for (; i + 4 <= end; i += 4){
    int p0 = packed[i], p1 = packed[i+1], p2 = packed[i+2], p3 = packed[i+3];
    float g0 = __half2float(gat[i]);
    float g1 = __half2float(gat[i+1]);
    float g2 = __half2float(gat[i+2]);
    float g3 = __half2float(gat[i+3]);
    float2 f0 = __half22float2(xrec2[(size_t)(p0 & 0xFFFF)*16 + l]);
    float2 f1 = __half22float2(xrec2[(size_t)(p1 & 0xFFFF)*16 + l]);
    float2 f2 = __half22float2(xrec2[(size_t)(p2 & 0xFFFF)*16 + l]);
    float2 f3 = __half22float2(xrec2[(size_t)(p3 & 0xFFFF)*16 + l]);
    ax = fmaf(f0.x, g0, ax); ay = fmaf(f0.y, g0, ay);
    ax = fmaf(f1.x, g1, ax); ay = fmaf(f1.y, g1, ay);
    ax = fmaf(f2.x, g2, ax); ay = fmaf(f2.y, g2, ay);
    ax = fmaf(f3.x, g3, ax); ay = fmaf(f3.y, g3, ay);
  }
  for (; i < end; i++){
    int p = packed[i];
    float g = __half2float(gat[i]);
    float2 fx = __half22float2(xrec2[(size_t)(p & 0xFFFF)*16 + l]);
    ax = fmaf(fx.x, g, ax); ay = fmaf(fx.y, g, ay);
  }
  int deg = end - beg;
  float inv = (deg > 0) ? 1.f/(float)deg : 0.f;
  // stage agg + x rows in LDS (wave-internal RAW: same 16-lane group writes & reads)
  aggs[n2][2*l]   = ax*inv;
  aggs[n2][2*l+1] = ay*inv;
  {
    float2 xv = *reinterpret_cast<const float2*>(&x[(size_t)node*ENCD + 2*l]);
    xss[n2][2*l]   = xv.x;
    xss[n2][2*l+1] = xv.y;
  }
  // linear: each lane computes outd/16 outputs for its node
  if (outd == 32){
    int k0 = 2*l;
    float a0 = bias[k0], a1 = bias[k0+1];
    #pragma unroll 8
    for (int j=0;j<32;j++){
      float xj = xss[n2][j];
      a0 = fmaf(xj, W[(size_t)j*32 + k0],   a0);
      a1 = fmaf(xj, W[(size_t)j*32 + k0+1], a1);
    }
    #pragma unroll 8
    for (int j=0;j<32;j++){
      float aj = aggs[n2][j];
      a0 = fmaf(aj, W[(size_t)(32+j)*32 + k0],   a0);
      a1 = fmaf(aj, W[(size_t)(32+j)*32 + k0+1], a1);
    }
    float2 o;
    o.x = a0 > 0.f ? a0 : 0.01f*a0;
    o.y = a1 > 0.f ? a1 : 0.01f*a1;
    *reinterpret_cast<float2*>(&out[(size_t)node*32 + k0]) = o;
  } else {
    float a0 = bias[l];
    #pragma unroll 8
    for (int j=0;j<32;j++){
      float xj = xss[n2][j];
      a0 = fmaf(xj, W[(size_t)j*16 + l], a0);
    }
    #pragma unroll 8
    for (int j=0;j<32;j++){
      float aj = aggs[n2][j];
      a0 = fmaf(aj, W[(size_t)(32+j)*16 + l], a0);
    }
    out[(size_t)node*16 + l] = a0 > 0.f ? a0 : 0.01f*a0;
  }
}

__global__ __launch_bounds__(256) void k_score(const float* __restrict__ x1, const float* __restrict__ x2,
    const int* __restrict__ users, const int* __restrict__ items, float* __restrict__ out, int Bn){
  int b = blockIdx.x*256 + threadIdx.x;
  if (b >= Bn) return;
  int u  = N_ENT + users[b];
  int it = items[b];
  const float* a1 = x1 + (size_t)u*32;
  const float* c1 = x1 + (size_t)it*32;
  const float* a2 = x2 + (size_t)u*16;
  const float* c2 = x2 + (size_t)it*16;
  float s = 0.f;
  #pragma unroll
  for (int q=0;q<8;q++){
    float4 va=ld4(a1+4*q), vb=ld4(c1+4*q);
    s = fmaf(va.x,vb.x,s); s = fmaf(va.y,vb.y,s); s = fmaf(va.z,vb.z,s); s = fmaf(va.w,vb.w,s);
  }
  #pragma unroll
  for (int q=0;q<4;q++){
    float4 va=ld4(a2+4*q), vb=ld4(c2+4*q);
    s = fmaf(va.x,vb.x,s); s = fmaf(va.y,vb.y,s); s = fmaf(va.z,vb.z,s); s = fmaf(va.w,vb.w,s);
  }
  out[b] = s;
}

extern "C" void kernel_launch(void* const* d_in, const int* in_sizes, int n_in,
                              void* d_out, int out_size, void* d_ws, size_t ws_size,
                              hipStream_t stream){
  const int*   users   = (const int*)d_in[0];
  const int*   items   = (const int*)d_in[1];
  const int*   esrc    = (const int*)d_in[2];
  const int*   edst    = (const int*)d_in[3];
  const int*   erel    = (const int*)d_in[4];
  const float* ent     = (const float*)d_in[5];
  const float* usr     = (const float*)d_in[6];
  const float* enc_W0  = (const float*)d_in[7];
  const float* enc_b0  = (const float*)d_in[8];
  const float* enc_W1  = (const float*)d_in[9];
  const float* enc_b1  = (const float*)d_in[10];
  const float* dec_W0  = (const float*)d_in[11];
  const float* dec_b0  = (const float*)d_in[12];
  const float* dec_W1  = (const float*)d_in[13];
  const float* dec_b1  = (const float*)d_in[14];
  const float* Wr1     = (const float*)d_in[15];
  const float* lin_W1  = (const float*)d_in[16];
  const float* lin_b1  = (const float*)d_in[17];
  const float* Wr2     = (const float*)d_in[18];
  const float* lin_W2  = (const float*)d_in[19];
  const float* lin_b2  = (const float*)d_in[20];
  const int E = in_sizes[2];
  const int B = in_sizes[0];

  char* wp = (char*)d_ws;
  auto carve = [&](size_t bytes)->char*{ char* p = wp; wp += (bytes + 255) & ~(size_t)255; return p; };
  float* enc    = (float*)carve((size_t)NN*32*4);
  float* x1     = (float*)carve((size_t)NN*32*4);
  float* x2     = (float*)carve((size_t)NN*16*4);
  float* wsum   = (float*)carve((size_t)2*RR*DD*4);
  float* dA     = (float*)carve((size_t)NN*RR*4);
  __half* dbrec = (__half*)carve((size_t)NN*RR*2);   // 32B/node src-side gate dots
  __half* xrec  = (__half*)carve((size_t)NN*32*2);   // 64B/node f16 features
  __half* gat   = (__half*)carve((size_t)E*2);       // per-edge gate stream
  int*   packed = (int*)  carve((size_t)E*4);
  unsigned* bktData = (unsigned*)carve((size_t)E*4);
  int*   bktCnt = (int*)  carve((size_t)2*NB*4);     // cnt[256] + fill[256], one memset
  int*   bktFill= bktCnt + NB;
  int*   rowp   = (int*)  carve(((size_t)NN+256)*4);

  const int nbT  = (E + 4095)/4096;   // 4096-edge tiles (bucketA)
  const int nbTh = (E + 8191)/8192;   // 8192-edge tiles (fused hist)
  const int nbAE = (NN + 63)/64;      // 938
  const int nbD  = (NN*RR + 255)/256;
  dim3 blk(256);

  hipMemsetAsync(d_out, 0, (size_t)out_size*sizeof(float), stream);
  hipMemsetAsync(bktCnt, 0, (size_t)2*NB*sizeof(int), stream);

  // fused AE + hist + wsum
  k_ae_hist<<<dim3(nbAE + nbTh + 4), dim3(512), 0, stream>>>(
      ent, usr, enc_W0, enc_b0, enc_W1, enc_b1, dec_W0, dec_b0, dec_W1, dec_b1,
      enc, ((float*)d_out) + B, edst, bktCnt, Wr1, Wr2, wsum, E, nbAE, nbTh);

  // CSR build via 256-bucket two-phase counting sort (scan folded into both kernels)
  k_bucketA<<<nbT, blk, 0, stream>>>(esrc, edst, erel, bktCnt, bktFill, bktData, E);
  k_buildB <<<NBU, blk, 0, stream>>>(bktData, bktCnt, rowp, packed);

  k_dots <<<nbD, blk, 0, stream>>>(enc, wsum, dA, dbrec, xrec);
  k_gates<<<NBU*4, blk, 0, stream>>>(packed, rowp, bktCnt, dA, dbrec, gat);
  k_aggl <<<(NN+15)/16, blk, 0, stream>>>((const __half2*)xrec, packed, gat, rowp, enc, lin_W1, lin_b1, x1, 32);

  k_dots <<<nbD, blk, 0, stream>>>(x1, wsum + RR*DD, dA, dbrec, xrec);
  k_gates<<<NBU*4, blk, 0, stream>>>(packed, rowp, bktCnt, dA, dbrec, gat);
  k_aggl <<<(NN+15)/16, blk, 0, stream>>>((const __half2*)xrec, packed, gat, rowp, x1, lin_W2, lin_b2, x2, 16);

  k_score<<<(B+255)/256, blk, 0, stream>>>(x1, x2, users, items, (float*)d_out, B);
}